// Round 8
// baseline (138.703 us; speedup 1.0000x reference)
//
#include <hip/hip_runtime.h>

#define Bn 16
#define Cn 64
#define Hn 128
#define Wn 128
#define HWn (Hn * Wn)

typedef __attribute__((ext_vector_type(8)))  short  short8;    // 8 bf16
typedef __attribute__((ext_vector_type(16))) float  floatx16;  // 32x32 C/D
typedef __attribute__((ext_vector_type(4)))  float  floatx4;
using int32x4 = int __attribute__((ext_vector_type(4)));

__device__ floatx4
llvm_amdgcn_raw_buffer_load_v4f32(int32x4 srsrc, int voffset, int soffset,
                                  int aux) __asm("llvm.amdgcn.raw.buffer.load.v4f32");

__device__ __forceinline__ int32x4 make_rsrc(const void* p, int bytes) {
    int32x4 r;
    r.x = (int)(unsigned)(uintptr_t)p;
    r.y = (int)((uintptr_t)p >> 32);   // stride=0
    r.z = bytes;                        // num_records
    r.w = 0x00020000;                   // raw dword SRD
    return r;
}

__device__ __forceinline__ unsigned short f2bf(float f) {  // RNE f32->bf16
    unsigned u = __float_as_uint(f);
    u += 0x7fffu + ((u >> 16) & 1u);
    return (unsigned short)(u >> 16);
}
__device__ __forceinline__ float lrelu(float v) { return v >= 0.f ? v : 0.1f * v; }

// ---------------------------------------------------------------------------
// Kernel-gen (unchanged, ~4us). Outputs:
//   kernP[b][c][12]  fp32 taps 0..8 (+pad), WcBF[o][c] bf16 RNE.
// ---------------------------------------------------------------------------
__global__ __launch_bounds__(192)
void gen_kern6(const float* __restrict__ d,
               const float* __restrict__ Wk1,
               const float* __restrict__ Wk2,
               const float* __restrict__ Wc,
               float* __restrict__ kernP,            // ws: [16][64][12]
               unsigned short* __restrict__ WcBF) {  // ws: [64][64] bf16
    const int b = blockIdx.x;
    const int r = blockIdx.y;
    const int t = threadIdx.x;
    __shared__ float hid_s[64];

    if (t < 64) {
        const float4* __restrict__ w4 = (const float4*)(Wk1 + (size_t)t * 64);
        const float*  __restrict__ db = d + b * 64;
        float s0 = 0.f, s1 = 0.f, s2 = 0.f, s3 = 0.f;
        #pragma unroll
        for (int j = 0; j < 16; ++j) {
            const float4 wv = w4[j];
            s0 += db[4 * j + 0] * wv.x;
            s1 += db[4 * j + 1] * wv.y;
            s2 += db[4 * j + 2] * wv.z;
            s3 += db[4 * j + 3] * wv.w;
        }
        hid_s[t] = lrelu((s0 + s1) + (s2 + s3));
    }
    __syncthreads();

    {
        const int o = r * 192 + t;
        const float4* __restrict__ w4 = (const float4*)(Wk2 + (size_t)o * 64);
        const float4* __restrict__ h4 = (const float4*)hid_s;
        float s0 = 0.f, s1 = 0.f, s2 = 0.f, s3 = 0.f;
        #pragma unroll
        for (int j = 0; j < 16; ++j) {
            const float4 wv = w4[j];
            const float4 hv = h4[j];
            s0 += hv.x * wv.x;
            s1 += hv.y * wv.y;
            s2 += hv.z * wv.z;
            s3 += hv.w * wv.w;
        }
        const int c = o / 9, tap = o - c * 9;
        kernP[b * 768 + c * 12 + tap] = (s0 + s1) + (s2 + s3);
    }

    if (b == 0 && r == 0) {
        for (int idx = t; idx < 4096; idx += 192)
            WcBF[idx] = f2bf(Wc[idx]);
    }
}

// ---------------------------------------------------------------------------
// Main fused conv, R8: R7 structure + (a) double-buffered tl -> ONE barrier
// per group (write->read; read->overwrite protected transitively by the
// barrier chain), (b) register prefetch of group g+1's x rows + kern row
// during group g's LDS/MFMA phase, (c) A-frags & bias hoisted.
// LDS 2 x 25.5KB = 51KB -> 3 blocks/CU (launch_bounds(256,3)).
// ---------------------------------------------------------------------------
__global__ __launch_bounds__(256, 3)
void da_mfma3(const float* __restrict__ x,
              const float* __restrict__ kernP,
              const unsigned short* __restrict__ WcBF,
              const float* __restrict__ bc,
              float* __restrict__ out) {
    const int t    = threadIdx.x;
    const int lane = t & 63;
    const int wv   = t >> 6;            // wave -> px tile
    const int col  = lane & 31;
    const int kh   = lane >> 5;
    const int bx   = blockIdx.x;
    const int h    = ((bx & 7) << 4) | (bx >> 3);   // XCD-band swizzle
    const int b    = blockIdx.y;

    __shared__ float tl[2][16 * 3 * 136];  // [buf][ch][dx][136]; px p at 4+p

    int rofsB[3];
    #pragma unroll
    for (int i = 0; i < 3; ++i) {
        const int hh = h + i - 1;
        rofsB[i] = (hh >= 0 && hh < Hn) ? hh * (Wn * 4) : 0x10000000;
    }

    const int32x4 rs = make_rsrc(x + (size_t)b * Cn * HWn, Cn * HWn * 4);

    // zero pad slots (p=-1 -> idx3, p=128 -> idx132) of BOTH buffers, once.
    // Visibility to readers is covered by group-0's post-write barrier.
    if (t < 192) {
        const int bi = t >= 96 ? 1 : 0;
        const int r  = t - bi * 96;
        const int ch = r / 6, rem = r - ch * 6;
        const int dx = rem >> 1, side = rem & 1;
        tl[bi][(ch * 3 + dx) * 136 + (side ? 132 : 3)] = 0.f;
    }

    // hoisted A-frags: afr[m][g], k = g*16 + kh*8 + j
    short8 afr[2][4];
    #pragma unroll
    for (int m = 0; m < 2; ++m)
        #pragma unroll
        for (int g = 0; g < 4; ++g)
            afr[m][g] = *(const short8*)(WcBF + (m * 32 + col) * 64 + g * 16 + kh * 8);

    // acc init = bias (D row o = m*32 + (r&3)+8*(r>>2)+4*kh)
    floatx16 acc[2];
    #pragma unroll
    for (int m = 0; m < 2; ++m)
        #pragma unroll
        for (int r = 0; r < 16; ++r)
            acc[m][r] = bc[m * 32 + (r & 3) + 8 * (r >> 2) + 4 * kh];

    const int sch = t >> 4;             // staging channel 0..15
    const int px0 = (t & 15) * 8;       // staging 8-px octet
    const float* __restrict__ kp = kernP + b * 768;
    const int px = wv * 32 + col;

    // ---- prefetch group 0 (x rows + kern row) ----
    float xa[3][8];
    floatx4 kc0, kc1; float kc8;
    {
        const int c = sch;
        #pragma unroll
        for (int r = 0; r < 3; ++r) {
            const int vo = (c << 16) + rofsB[r] + px0 * 4;
            const floatx4 va = llvm_amdgcn_raw_buffer_load_v4f32(rs, vo, 0, 0);
            const floatx4 vb = llvm_amdgcn_raw_buffer_load_v4f32(rs, vo + 16, 0, 0);
            xa[r][0] = va.x; xa[r][1] = va.y; xa[r][2] = va.z; xa[r][3] = va.w;
            xa[r][4] = vb.x; xa[r][5] = vb.y; xa[r][6] = vb.z; xa[r][7] = vb.w;
        }
        const floatx4* k4 = (const floatx4*)(kp + c * 12);
        kc0 = k4[0]; kc1 = k4[1]; kc8 = ((const float*)k4)[8];
    }

    #pragma unroll
    for (int g = 0; g < 4; ++g) {
        float* __restrict__ tb = tl[g & 1];

        // ---- column sums from registers ----
        float t0[8], t1[8], t2[8];
        #pragma unroll
        for (int i = 0; i < 8; ++i) {
            t0[i] = kc0.x * xa[0][i] + kc0.w * xa[1][i] + kc1.z * xa[2][i]; // taps 0,3,6
            t1[i] = kc0.y * xa[0][i] + kc1.x * xa[1][i] + kc1.w * xa[2][i]; // taps 1,4,7
            t2[i] = kc0.z * xa[0][i] + kc1.y * xa[1][i] + kc8   * xa[2][i]; // taps 2,5,8
        }
        {
            const int base = (sch * 3) * 136 + 4 + px0;
            *(float4*)&tb[base]       = make_float4(t0[0], t0[1], t0[2], t0[3]);
            *(float4*)&tb[base + 4]   = make_float4(t0[4], t0[5], t0[6], t0[7]);
            *(float4*)&tb[base + 136] = make_float4(t1[0], t1[1], t1[2], t1[3]);
            *(float4*)&tb[base + 140] = make_float4(t1[4], t1[5], t1[6], t1[7]);
            *(float4*)&tb[base + 272] = make_float4(t2[0], t2[1], t2[2], t2[3]);
            *(float4*)&tb[base + 276] = make_float4(t2[4], t2[5], t2[6], t2[7]);
        }
        __syncthreads();   // write -> read (only barrier per group)

        // ---- prefetch group g+1 while compute runs ----
        if (g < 3) {
            const int c = (g + 1) * 16 + sch;
            #pragma unroll
            for (int r = 0; r < 3; ++r) {
                const int vo = (c << 16) + rofsB[r] + px0 * 4;
                const floatx4 va = llvm_amdgcn_raw_buffer_load_v4f32(rs, vo, 0, 0);
                const floatx4 vb = llvm_amdgcn_raw_buffer_load_v4f32(rs, vo + 16, 0, 0);
                xa[r][0] = va.x; xa[r][1] = va.y; xa[r][2] = va.z; xa[r][3] = va.w;
                xa[r][4] = vb.x; xa[r][5] = vb.y; xa[r][6] = vb.z; xa[r][7] = vb.w;
            }
            const floatx4* k4 = (const floatx4*)(kp + c * 12);
            kc0 = k4[0]; kc1 = k4[1]; kc8 = ((const float*)k4)[8];
        }

        // ---- B-frag from tl + 2 MFMA ----
        short8 bfr;
        #pragma unroll
        for (int j = 0; j < 8; ++j) {
            const int cl = kh * 8 + j;
            const int bse = (cl * 3) * 136 + 4 + px;
            const float dw = tb[bse - 1]       // t0[p-1]
                           + tb[bse + 136]     // t1[p]
                           + tb[bse + 273];    // t2[p+1]
            bfr[j] = (short)f2bf(lrelu(dw));
        }
        acc[0] = __builtin_amdgcn_mfma_f32_32x32x16_bf16(afr[0][g], bfr, acc[0], 0, 0, 0);
        acc[1] = __builtin_amdgcn_mfma_f32_32x32x16_bf16(afr[1][g], bfr, acc[1], 0, 0, 0);
    }

    // ---- store: 32 contiguous px per o-row (full 128B lines) ----
    float* __restrict__ ob = out + (size_t)b * Cn * HWn + h * Wn + px;
    #pragma unroll
    for (int m = 0; m < 2; ++m)
        #pragma unroll
        for (int r = 0; r < 16; ++r) {
            const int o = m * 32 + (r & 3) + 8 * (r >> 2) + 4 * kh;
            ob[(size_t)o * HWn] = acc[m][r];
        }
}

// ---------------------------------------------------------------------------
extern "C" void kernel_launch(void* const* d_in, const int* in_sizes, int n_in,
                              void* d_out, int out_size, void* d_ws, size_t ws_size,
                              hipStream_t stream) {
    const float* x   = (const float*)d_in[0];
    const float* d   = (const float*)d_in[1];
    const float* Wk1 = (const float*)d_in[2];
    const float* Wk2 = (const float*)d_in[3];
    const float* Wc  = (const float*)d_in[4];
    const float* bc  = (const float*)d_in[5];
    float* out = (float*)d_out;
    float*          kernP = (float*)d_ws;                              // 16*768 fp32
    unsigned short* WcBF  = (unsigned short*)((float*)d_ws + Bn * 768); // 64*64 bf16

    gen_kern6<<<dim3(Bn, 3), dim3(192), 0, stream>>>(d, Wk1, Wk2, Wc, kernP, WcBF);
    da_mfma3<<<dim3(Hn, Bn), dim3(256), 0, stream>>>(x, kernP, WcBF, bc, out);
}